// Round 11
// baseline (247.726 us; speedup 1.0000x reference)
//
#include <hip/hip_runtime.h>
#include <stdint.h>

#define DEVFN __device__ __forceinline__

typedef __attribute__((ext_vector_type(8))) __bf16 bf16x8;
typedef __attribute__((ext_vector_type(8))) short short8;
typedef __attribute__((ext_vector_type(4))) float f32x4;
typedef __attribute__((ext_vector_type(4))) unsigned int u32x4;

DEVFN unsigned short f2bf(float f) {
  union { float f; unsigned u; } v; v.f = f;
  return (unsigned short)((v.u + 0x7FFFu + ((v.u >> 16) & 1u)) >> 16);
}

// global -> LDS direct copy, 16B per lane. Dest must be linear in lane order.
DEVFN void gload_lds16(const void* g, void* l) {
  __builtin_amdgcn_global_load_lds(
      (const __attribute__((address_space(1))) void*)(uintptr_t)g,
      (__attribute__((address_space(3))) void*)(uint32_t)(uintptr_t)l,
      16, 0, 0);
}

// ---------------- prep kernels ----------------

__global__ void k_cast_x(const float* __restrict__ x, short* __restrict__ xb, int n8) {
  int i = blockIdx.x * blockDim.x + threadIdx.x;
  if (i >= n8) return;
  const f32x4* xf = (const f32x4*)x;
  f32x4 a = xf[2 * i], b = xf[2 * i + 1];
  short8 s;
  s[0] = (short)f2bf(a[0]); s[1] = (short)f2bf(a[1]);
  s[2] = (short)f2bf(a[2]); s[3] = (short)f2bf(a[3]);
  s[4] = (short)f2bf(b[0]); s[5] = (short)f2bf(b[1]);
  s[6] = (short)f2bf(b[2]); s[7] = (short)f2bf(b[3]);
  ((short8*)xb)[i] = s;
}

// w[R][C] (f32) -> wt[C][R] (bf16)
__global__ void k_transpose_bf(const float* __restrict__ w, short* __restrict__ wt, int R, int C) {
  int i = blockIdx.x * blockDim.x + threadIdx.x;
  if (i >= R * C) return;
  int c = i / R, r = i - c * R;
  wt[i] = (short)f2bf(w[(size_t)r * C + c]);
}

// ---------------- GEMM: C[M][N] = A[M][K] * Bt[N][K]^T ----------------
// Block tile 128 x (NB*32), BK=32, 256 threads (4 waves), per-wave 64 x (NB*16).
// 3-buffer pipeline, counted vmcnt; T1 XCD swizzle; T2 slot-swizzle.

template <int BF16_OUT, int NB>
__global__ __launch_bounds__(256, NB == 8 ? 2 : 3)
void k_gemm(const short* __restrict__ A, const short* __restrict__ Bt,
            unsigned short* __restrict__ Cb, float* __restrict__ Cf,
            const float* __restrict__ bias, int M, int N, int K) {
  constexpr int BN = NB * 32;          // 256 or 128
  constexpr int BCH = NB / 2;          // B staging chunks per thread (4 or 2)
  __shared__ short As[3][128 * 32];
  __shared__ short Bs[3][BN * 32];
  const int tid = threadIdx.x;
  const int l = tid & 63, w = tid >> 6;
  const int ntile = N / BN;
  // XCD-chunked swizzle (T1): grid % 8 == 0 (1536 / 768).
  const int nwg = gridDim.x, cpx = nwg >> 3;
  const int bid = (blockIdx.x & 7) * cpx + (blockIdx.x >> 3);
  const int mt = bid / ntile, nt = bid % ntile;
  const int m0 = mt << 7, n0 = nt * BN;
  const int wm = (w >> 1) << 6, wn = (w & 1) * (NB * 16);

  f32x4 acc[4][NB];
#pragma unroll
  for (int i = 0; i < 4; i++)
#pragma unroll
    for (int j = 0; j < NB; j++) acc[i][j] = (f32x4){0.f, 0.f, 0.f, 0.f};

  const int nsteps = K >> 5;  // 12 (GEMM1) or 16 (GEMM2)

  auto stage = [&](int buf, int t) {
#pragma unroll
    for (int c = 0; c < 2; ++c) {
      int ch = tid + c * 256;
      int row = ch >> 2;
      int sl = (ch & 3) ^ ((row >> 1) & 3);  // inverse-swizzled source slot
      gload_lds16(A + (size_t)(m0 + row) * K + t * 32 + sl * 8, &As[buf][ch * 8]);
    }
#pragma unroll
    for (int c = 0; c < BCH; ++c) {
      int ch = tid + c * 256;
      int row = ch >> 2;
      int sl = (ch & 3) ^ ((row >> 1) & 3);
      gload_lds16(Bt + (size_t)(n0 + row) * K + t * 32 + sl * 8, &Bs[buf][ch * 8]);
    }
  };
  // swizzled read slot: rows base+(l&15), base%16==0 -> (row>>1)&3 == (l>>1)&3
  const int sp8 = (((l >> 4) ^ ((l >> 1) & 3)) << 3);
  auto compute = [&](int buf) {
    bf16x8 af[4], bfr[NB];
#pragma unroll
    for (int i = 0; i < 4; i++)
      af[i] = *(const bf16x8*)&As[buf][(wm + i * 16 + (l & 15)) * 32 + sp8];
#pragma unroll
    for (int j = 0; j < NB; j++)
      bfr[j] = *(const bf16x8*)&Bs[buf][(wn + j * 16 + (l & 15)) * 32 + sp8];
#pragma unroll
    for (int i = 0; i < 4; i++)
#pragma unroll
      for (int j = 0; j < NB; j++)
        acc[i][j] = __builtin_amdgcn_mfma_f32_16x16x32_bf16(af[i], bfr[j], acc[i][j], 0, 0, 0);
  };

  // prologue: 2 tiles in flight ((2+BCH) gload_lds16 each per thread)
  stage(0, 0);
  stage(1, 1);
#pragma unroll 1
  for (int t = 0; t < nsteps; ++t) {
    // wait for tile-t's (2+BCH) loads; keep tile-(t+1)'s in flight
    if (t + 1 < nsteps) {
      if constexpr (NB == 8)
        asm volatile("s_waitcnt vmcnt(6)" ::: "memory");
      else
        asm volatile("s_waitcnt vmcnt(4)" ::: "memory");
    } else {
      asm volatile("s_waitcnt vmcnt(0)" ::: "memory");
    }
    __builtin_amdgcn_sched_barrier(0);
    __builtin_amdgcn_s_barrier();  // all waves' t-loads done; all done reading buf[t-1]
    __builtin_amdgcn_sched_barrier(0);
    if (t + 2 < nsteps) stage((t + 2) % 3, t + 2);  // overwrites buf[(t-1)%3]: safe post-barrier
    compute(t % 3);
  }

#pragma unroll
  for (int i = 0; i < 4; i++) {
    int mrow = m0 + wm + i * 16 + ((l >> 4) << 2);
#pragma unroll
    for (int j = 0; j < NB; j++) {
      int ncol = n0 + wn + j * 16 + (l & 15);
#pragma unroll
      for (int r = 0; r < 4; r++) {
        if (BF16_OUT) {
          Cb[(size_t)(mrow + r) * N + ncol] = f2bf(acc[i][j][r]);
        } else {
          Cf[(size_t)(mrow + r) * N + ncol] = acc[i][j][r] + bias[ncol];
        }
      }
    }
  }
}

// ---------------- fused attention per (bp, head) ----------------
// qkv[token][1536]: Q at h*64, K at 512+h*64, V at 1024+h*64 (bf16).
// 512 threads = 8 waves; wave w handles q rows [w*32, w*32+32) in 2 iters of 16.
//
// SWAPPED QK^T: S^T = mfma(K, Q) puts S[q=l&15][k=kt*16+g*4+r] in lane
// registers; PV's A-fragment comes from the lane's OWN registers under slot
// permutation pi(k)=g*8+(k&16?4:0)+(k&3), with V staged pi-permuted.
// Validated correct in round 10 (absmax unchanged). Round 10's 155us was a
// CODEGEN failure: the union{short8;bf16x8} pk was an un-promoted alloca ->
// scratch (262MB writes). Fixed here with pure-SSA packing: u32 words +
// constant-index ext-vector insert + __builtin_bit_cast (no memory object).

__global__ __launch_bounds__(512, 2)
void k_attn(const short* __restrict__ qkv, unsigned short* __restrict__ O) {
  __shared__ short Kl[256 * 64];        // [kcol][64d], XOR-swizzled 16B slots
  __shared__ short Vt[64 * 256];        // [d][pi(k)], XOR-swizzled 16B slots

  const int tid = threadIdx.x, l = tid & 63, w = tid >> 6;
  const int g = (l >> 4) & 3;
  const int bh = blockIdx.x;
  const int bp = bh >> 3, h = bh & 7;
  const size_t tokbase = (size_t)bp * 256 * 1536;
  const int qoff = h * 64, koff = 512 + h * 64, voff = 1024 + h * 64;

  // stage K: linear LDS dest, inverse-swizzled global source (slot ^= row&7)
#pragma unroll
  for (int c = 0; c < 4; ++c) {
    int ch = tid + c * 512;
    int row = ch >> 3, s = ch & 7;
    int sg = s ^ (row & 7);
    gload_lds16(qkv + tokbase + (size_t)row * 1536 + koff + sg * 8, &Kl[ch * 8]);
  }
  // stage V transposed with pi(k): Vt[d][kc*32 + pos], pos = gg*8+(u&16?4:0)+(u&3),
  // 16B slot (kc*4+gg) XOR-swizzled with (d&15).
#pragma unroll
  for (int c = 0; c < 4; ++c) {
    int ch = tid + c * 512;
    int row = ch >> 3, d0 = (ch & 7) * 8;
    short8 v = *(const short8*)(qkv + tokbase + (size_t)row * 1536 + voff + d0);
    int kc = row >> 5, u = row & 31;
    int gg = (u >> 2) & 3;
    int off = ((u & 16) ? 4 : 0) + (u & 3);
#pragma unroll
    for (int j = 0; j < 8; ++j) {
      int d = d0 + j;
      int sl = (kc * 4 + gg) ^ (d & 15);
      Vt[d * 256 + sl * 8 + off] = v[j];
    }
  }
  __syncthreads();

  const float CEXP = 0.125f * 1.44269504f;  // SCALE * log2(e)

#pragma unroll 1
  for (int it = 0; it < 2; ++it) {
    const int q0 = w * 32 + it * 16;
    bf16x8 qa[2];
#pragma unroll
    for (int dc = 0; dc < 2; ++dc)
      qa[dc] = *(const bf16x8*)(qkv + tokbase + (size_t)(q0 + (l & 15)) * 1536 + qoff +
                                dc * 32 + (l >> 4) * 8);
    // S^T = K Q^T: D[kcol][q] -> lane holds S[q=l&15][k=kt*16+g*4+r]
    f32x4 s[16];
#pragma unroll
    for (int kt = 0; kt < 16; kt++) s[kt] = (f32x4){0.f, 0.f, 0.f, 0.f};
#pragma unroll
    for (int dc = 0; dc < 2; ++dc) {
#pragma unroll
      for (int kt = 0; kt < 16; ++kt) {
        int kcol = kt * 16 + (l & 15);
        int sl = (dc * 4 + (l >> 4)) ^ (kcol & 7);
        bf16x8 kb = *(const bf16x8*)&Kl[kcol * 64 + sl * 8];
        s[kt] = __builtin_amdgcn_mfma_f32_16x16x32_bf16(kb, qa[dc], s[kt], 0, 0, 0);
      }
    }
    // softmax over k for this lane's q=l&15: local 64-value reduce + 2 shfl
    float mx = s[0][0];
#pragma unroll
    for (int kt = 0; kt < 16; kt++)
#pragma unroll
      for (int r = 0; r < 4; r++) mx = fmaxf(mx, s[kt][r]);
    mx = fmaxf(mx, __shfl_xor(mx, 16, 64));
    mx = fmaxf(mx, __shfl_xor(mx, 32, 64));
    float sum = 0.f;
#pragma unroll
    for (int kt = 0; kt < 16; kt++)
#pragma unroll
      for (int r = 0; r < 4; r++) {
        float p = exp2f((s[kt][r] - mx) * CEXP);
        s[kt][r] = p;
        sum += p;
      }
    sum += __shfl_xor(sum, 16, 64);
    sum += __shfl_xor(sum, 32, 64);
    float rs = 1.0f / sum;

    // PV: A-fragment from OWN registers (slot perm pi); B = Vt (pi-stored).
    f32x4 o[4];
#pragma unroll
    for (int dt = 0; dt < 4; dt++) o[dt] = (f32x4){0.f, 0.f, 0.f, 0.f};
#pragma unroll
    for (int kc = 0; kc < 8; ++kc) {
      // SSA bf16x8 packing (no union/alloca): u32 = lo | hi<<16 per pair.
      u32x4 pw;
      pw[0] = (unsigned)f2bf(s[2 * kc][0])     | ((unsigned)f2bf(s[2 * kc][1]) << 16);
      pw[1] = (unsigned)f2bf(s[2 * kc][2])     | ((unsigned)f2bf(s[2 * kc][3]) << 16);
      pw[2] = (unsigned)f2bf(s[2 * kc + 1][0]) | ((unsigned)f2bf(s[2 * kc + 1][1]) << 16);
      pw[3] = (unsigned)f2bf(s[2 * kc + 1][2]) | ((unsigned)f2bf(s[2 * kc + 1][3]) << 16);
      bf16x8 pa = __builtin_bit_cast(bf16x8, pw);
#pragma unroll
      for (int dt = 0; dt < 4; ++dt) {
        int d = dt * 16 + (l & 15);
        int sl = (kc * 4 + g) ^ (d & 15);
        bf16x8 vb = *(const bf16x8*)&Vt[d * 256 + sl * 8];
        o[dt] = __builtin_amdgcn_mfma_f32_16x16x32_bf16(pa, vb, o[dt], 0, 0, 0);
      }
    }
    // epilogue: O rows q = q0 + g*4 + r, col d = dt*16 + (l&15);
    // rs lives at lanes with (lane&15)==q -> fetch via shfl.
    float rsq[4];
#pragma unroll
    for (int r = 0; r < 4; ++r)
      rsq[r] = __shfl(rs, (l & 48) | (g * 4 + r), 64);
#pragma unroll
    for (int dt = 0; dt < 4; dt++) {
#pragma unroll
      for (int r = 0; r < 4; r++) {
        int qrow = q0 + g * 4 + r;
        int d = dt * 16 + (l & 15);
        O[(size_t)(bp * 256 + qrow) * 512 + h * 64 + d] = f2bf(o[dt][r] * rsq[r]);
      }
    }
  }
}

// ---------------- launch ----------------

extern "C" void kernel_launch(void* const* d_in, const int* in_sizes, int n_in,
                              void* d_out, int out_size, void* d_ws, size_t ws_size,
                              hipStream_t stream) {
  const float* x    = (const float*)d_in[0];
  const float* wqkv = (const float*)d_in[1];
  const float* wout = (const float*)d_in[2];
  const float* bout = (const float*)d_in[3];
  float* out = (float*)d_out;
  char* ws = (char*)d_ws;

  // ws layout (O overlaps Xb/Wqt, which are dead after GEMM1): total ~134.6 MB
  short* Wot = (short*)(ws);                          //   0.39 MB [384][512]
  short* Xb  = (short*)(ws + 393216);                 //  25.17 MB [32768][384]
  short* Wqt = (short*)(ws + 25559040);               //   1.18 MB [1536][384]
  unsigned short* O = (unsigned short*)(ws + 393216); //  33.55 MB [32768][512]
  short* QKV = (short*)(ws + 33947648);               // 100.66 MB [32768][1536]

  k_cast_x<<<6144, 256, 0, stream>>>(x, Xb, 1572864);
  k_transpose_bf<<<2304, 256, 0, stream>>>(wqkv, Wqt, 384, 1536);
  k_transpose_bf<<<768, 256, 0, stream>>>(wout, Wot, 512, 384);
  // GEMM1: 128x256 tiles -> (32768/128)*(1536/256) = 1536 blocks (%8==0)
  k_gemm<1, 8><<<1536, 256, 0, stream>>>(Xb, Wqt, (unsigned short*)QKV, nullptr, nullptr,
                                         32768, 1536, 384);
  k_attn<<<1024, 512, 0, stream>>>(QKV, O);
  // GEMM2: 128x128 tiles -> (32768/128)*(384/128) = 768 blocks (%8==0)
  k_gemm<0, 4><<<768, 256, 0, stream>>>((const short*)O, Wot, nullptr, out, bout,
                                        32768, 384, 512);
  (void)in_sizes; (void)n_in; (void)out_size; (void)ws_size;
}

// Round 12
// 246.901 us; speedup vs baseline: 1.0033x; 1.0033x over previous
//
#include <hip/hip_runtime.h>
#include <stdint.h>

#define DEVFN __device__ __forceinline__

typedef __attribute__((ext_vector_type(8))) __bf16 bf16x8;
typedef __attribute__((ext_vector_type(8))) short short8;
typedef __attribute__((ext_vector_type(4))) float f32x4;
typedef __attribute__((ext_vector_type(4))) unsigned int u32x4;

DEVFN unsigned short f2bf(float f) {
  union { float f; unsigned u; } v; v.f = f;
  return (unsigned short)((v.u + 0x7FFFu + ((v.u >> 16) & 1u)) >> 16);
}

// global -> LDS direct copy, 16B per lane. Dest must be linear in lane order.
DEVFN void gload_lds16(const void* g, void* l) {
  __builtin_amdgcn_global_load_lds(
      (const __attribute__((address_space(1))) void*)(uintptr_t)g,
      (__attribute__((address_space(3))) void*)(uint32_t)(uintptr_t)l,
      16, 0, 0);
}

// ---------------- prep kernels ----------------

__global__ void k_cast_x(const float* __restrict__ x, short* __restrict__ xb, int n8) {
  int i = blockIdx.x * blockDim.x + threadIdx.x;
  if (i >= n8) return;
  const f32x4* xf = (const f32x4*)x;
  f32x4 a = xf[2 * i], b = xf[2 * i + 1];
  short8 s;
  s[0] = (short)f2bf(a[0]); s[1] = (short)f2bf(a[1]);
  s[2] = (short)f2bf(a[2]); s[3] = (short)f2bf(a[3]);
  s[4] = (short)f2bf(b[0]); s[5] = (short)f2bf(b[1]);
  s[6] = (short)f2bf(b[2]); s[7] = (short)f2bf(b[3]);
  ((short8*)xb)[i] = s;
}

// w[R][C] (f32) -> wt[C][R] (bf16)
__global__ void k_transpose_bf(const float* __restrict__ w, short* __restrict__ wt, int R, int C) {
  int i = blockIdx.x * blockDim.x + threadIdx.x;
  if (i >= R * C) return;
  int c = i / R, r = i - c * R;
  wt[i] = (short)f2bf(w[(size_t)r * C + c]);
}

// ---------------- GEMM: C[M][N] = A[M][K] * Bt[N][K]^T ----------------
// Block tile 128 x (NB*32), BK=32, 256 threads (4 waves), per-wave 64 x (NB*16).
// 3-buffer pipeline, counted vmcnt; T1 XCD swizzle; T2 slot-swizzle.

template <int BF16_OUT, int NB>
__global__ __launch_bounds__(256, NB == 8 ? 2 : 3)
void k_gemm(const short* __restrict__ A, const short* __restrict__ Bt,
            unsigned short* __restrict__ Cb, float* __restrict__ Cf,
            const float* __restrict__ bias, int M, int N, int K) {
  constexpr int BN = NB * 32;          // 256 or 128
  constexpr int BCH = NB / 2;          // B staging chunks per thread (4 or 2)
  __shared__ short As[3][128 * 32];
  __shared__ short Bs[3][BN * 32];
  const int tid = threadIdx.x;
  const int l = tid & 63, w = tid >> 6;
  const int ntile = N / BN;
  // XCD-chunked swizzle (T1): grid % 8 == 0 (1536 / 768).
  const int nwg = gridDim.x, cpx = nwg >> 3;
  const int bid = (blockIdx.x & 7) * cpx + (blockIdx.x >> 3);
  const int mt = bid / ntile, nt = bid % ntile;
  const int m0 = mt << 7, n0 = nt * BN;
  const int wm = (w >> 1) << 6, wn = (w & 1) * (NB * 16);

  f32x4 acc[4][NB];
#pragma unroll
  for (int i = 0; i < 4; i++)
#pragma unroll
    for (int j = 0; j < NB; j++) acc[i][j] = (f32x4){0.f, 0.f, 0.f, 0.f};

  const int nsteps = K >> 5;  // 12 (GEMM1) or 16 (GEMM2)

  auto stage = [&](int buf, int t) {
#pragma unroll
    for (int c = 0; c < 2; ++c) {
      int ch = tid + c * 256;
      int row = ch >> 2;
      int sl = (ch & 3) ^ ((row >> 1) & 3);  // inverse-swizzled source slot
      gload_lds16(A + (size_t)(m0 + row) * K + t * 32 + sl * 8, &As[buf][ch * 8]);
    }
#pragma unroll
    for (int c = 0; c < BCH; ++c) {
      int ch = tid + c * 256;
      int row = ch >> 2;
      int sl = (ch & 3) ^ ((row >> 1) & 3);
      gload_lds16(Bt + (size_t)(n0 + row) * K + t * 32 + sl * 8, &Bs[buf][ch * 8]);
    }
  };
  // swizzled read slot: rows base+(l&15), base%16==0 -> (row>>1)&3 == (l>>1)&3
  const int sp8 = (((l >> 4) ^ ((l >> 1) & 3)) << 3);
  auto compute = [&](int buf) {
    bf16x8 af[4], bfr[NB];
#pragma unroll
    for (int i = 0; i < 4; i++)
      af[i] = *(const bf16x8*)&As[buf][(wm + i * 16 + (l & 15)) * 32 + sp8];
#pragma unroll
    for (int j = 0; j < NB; j++)
      bfr[j] = *(const bf16x8*)&Bs[buf][(wn + j * 16 + (l & 15)) * 32 + sp8];
#pragma unroll
    for (int i = 0; i < 4; i++)
#pragma unroll
      for (int j = 0; j < NB; j++)
        acc[i][j] = __builtin_amdgcn_mfma_f32_16x16x32_bf16(af[i], bfr[j], acc[i][j], 0, 0, 0);
  };

  // prologue: 2 tiles in flight ((2+BCH) gload_lds16 each per thread)
  stage(0, 0);
  stage(1, 1);
#pragma unroll 1
  for (int t = 0; t < nsteps; ++t) {
    // wait for tile-t's (2+BCH) loads; keep tile-(t+1)'s in flight
    if (t + 1 < nsteps) {
      if constexpr (NB == 8)
        asm volatile("s_waitcnt vmcnt(6)" ::: "memory");
      else
        asm volatile("s_waitcnt vmcnt(4)" ::: "memory");
    } else {
      asm volatile("s_waitcnt vmcnt(0)" ::: "memory");
    }
    __builtin_amdgcn_sched_barrier(0);
    __builtin_amdgcn_s_barrier();  // all waves' t-loads done; all done reading buf[t-1]
    __builtin_amdgcn_sched_barrier(0);
    if (t + 2 < nsteps) stage((t + 2) % 3, t + 2);  // overwrites buf[(t-1)%3]: safe post-barrier
    compute(t % 3);
  }

#pragma unroll
  for (int i = 0; i < 4; i++) {
    int mrow = m0 + wm + i * 16 + ((l >> 4) << 2);
#pragma unroll
    for (int j = 0; j < NB; j++) {
      int ncol = n0 + wn + j * 16 + (l & 15);
#pragma unroll
      for (int r = 0; r < 4; r++) {
        if (BF16_OUT) {
          Cb[(size_t)(mrow + r) * N + ncol] = f2bf(acc[i][j][r]);
        } else {
          Cf[(size_t)(mrow + r) * N + ncol] = acc[i][j][r] + bias[ncol];
        }
      }
    }
  }
}

// ---------------- fused attention per (bp, head) ----------------
// qkv[token][1536]: Q at h*64, K at 512+h*64, V at 1024+h*64 (bf16).
// 512 threads = 8 waves; wave w handles q rows [w*32, w*32+32) in 2 iters of 16.
//
// SWAPPED QK^T: S^T = mfma(K, Q) puts S[q=l&15][k=kt*16+g*4+r] in lane
// registers; PV's A-fragment comes from the lane's OWN registers under slot
// permutation pi(k)=g*8+(k&16?4:0)+(k&3), with V staged pi-permuted
// (validated: absmax unchanged since round 10).
//
// LIVENESS FIX (rounds 10/11 spilled s[16] wholesale: VGPR=128=cap, 228MB
// scratch): exp+sum+PACK fused in one loop so the 64 f32 of s[] die
// progressively (8 f32 -> 4 u32 per kc); PV holds only pa[8] (32 regs) + o.
// Peak live ~70-88 regs in every phase, under the 128 cap at 2 blocks/CU.

__global__ __launch_bounds__(512, 2)
void k_attn(const short* __restrict__ qkv, unsigned short* __restrict__ O) {
  __shared__ short Kl[256 * 64];        // [kcol][64d], XOR-swizzled 16B slots
  __shared__ short Vt[64 * 256];        // [d][pi(k)], XOR-swizzled 16B slots

  const int tid = threadIdx.x, l = tid & 63, w = tid >> 6;
  const int g = (l >> 4) & 3;
  const int bh = blockIdx.x;
  const int bp = bh >> 3, h = bh & 7;
  const size_t tokbase = (size_t)bp * 256 * 1536;
  const int qoff = h * 64, koff = 512 + h * 64, voff = 1024 + h * 64;

  // stage K: linear LDS dest, inverse-swizzled global source (slot ^= row&7)
#pragma unroll
  for (int c = 0; c < 4; ++c) {
    int ch = tid + c * 512;
    int row = ch >> 3, s = ch & 7;
    int sg = s ^ (row & 7);
    gload_lds16(qkv + tokbase + (size_t)row * 1536 + koff + sg * 8, &Kl[ch * 8]);
  }
  // stage V transposed with pi(k): Vt[d][kc*32 + pos], pos = gg*8+(u&16?4:0)+(u&3),
  // 16B slot (kc*4+gg) XOR-swizzled with (d&15).
#pragma unroll
  for (int c = 0; c < 4; ++c) {
    int ch = tid + c * 512;
    int row = ch >> 3, d0 = (ch & 7) * 8;
    short8 v = *(const short8*)(qkv + tokbase + (size_t)row * 1536 + voff + d0);
    int kc = row >> 5, u = row & 31;
    int gg = (u >> 2) & 3;
    int off = ((u & 16) ? 4 : 0) + (u & 3);
#pragma unroll
    for (int j = 0; j < 8; ++j) {
      int d = d0 + j;
      int sl = (kc * 4 + gg) ^ (d & 15);
      Vt[d * 256 + sl * 8 + off] = v[j];
    }
  }
  __syncthreads();

  const float CEXP = 0.125f * 1.44269504f;  // SCALE * log2(e)

#pragma unroll 1
  for (int it = 0; it < 2; ++it) {
    const int q0 = w * 32 + it * 16;
    bf16x8 qa[2];
#pragma unroll
    for (int dc = 0; dc < 2; ++dc)
      qa[dc] = *(const bf16x8*)(qkv + tokbase + (size_t)(q0 + (l & 15)) * 1536 + qoff +
                                dc * 32 + (l >> 4) * 8);
    // S^T = K Q^T: D[kcol][q] -> lane holds S[q=l&15][k=kt*16+g*4+r]
    f32x4 s[16];
#pragma unroll
    for (int kt = 0; kt < 16; kt++) s[kt] = (f32x4){0.f, 0.f, 0.f, 0.f};
#pragma unroll
    for (int dc = 0; dc < 2; ++dc) {
#pragma unroll
      for (int kt = 0; kt < 16; ++kt) {
        int kcol = kt * 16 + (l & 15);
        int sl = (dc * 4 + (l >> 4)) ^ (kcol & 7);
        bf16x8 kb = *(const bf16x8*)&Kl[kcol * 64 + sl * 8];
        s[kt] = __builtin_amdgcn_mfma_f32_16x16x32_bf16(kb, qa[dc], s[kt], 0, 0, 0);
      }
    }
    // softmax max over k for this lane's q=l&15 (local 64 + 2 shfl)
    float mx = s[0][0];
#pragma unroll
    for (int kt = 0; kt < 16; kt++)
#pragma unroll
      for (int r = 0; r < 4; r++) mx = fmaxf(mx, s[kt][r]);
    mx = fmaxf(mx, __shfl_xor(mx, 16, 64));
    mx = fmaxf(mx, __shfl_xor(mx, 32, 64));

    // exp + sum + EAGER bf16 pack: s[] f32 die here (8 f32 -> 4 u32 per kc),
    // so PV never needs the f32 scores resident.
    u32x4 pa[8];
    float sum = 0.f;
#pragma unroll
    for (int kc = 0; kc < 8; ++kc) {
      float p0 = exp2f((s[2 * kc][0] - mx) * CEXP);
      float p1 = exp2f((s[2 * kc][1] - mx) * CEXP);
      float p2 = exp2f((s[2 * kc][2] - mx) * CEXP);
      float p3 = exp2f((s[2 * kc][3] - mx) * CEXP);
      float p4 = exp2f((s[2 * kc + 1][0] - mx) * CEXP);
      float p5 = exp2f((s[2 * kc + 1][1] - mx) * CEXP);
      float p6 = exp2f((s[2 * kc + 1][2] - mx) * CEXP);
      float p7 = exp2f((s[2 * kc + 1][3] - mx) * CEXP);
      sum += ((p0 + p1) + (p2 + p3)) + ((p4 + p5) + (p6 + p7));
      u32x4 pw;
      pw[0] = (unsigned)f2bf(p0) | ((unsigned)f2bf(p1) << 16);
      pw[1] = (unsigned)f2bf(p2) | ((unsigned)f2bf(p3) << 16);
      pw[2] = (unsigned)f2bf(p4) | ((unsigned)f2bf(p5) << 16);
      pw[3] = (unsigned)f2bf(p6) | ((unsigned)f2bf(p7) << 16);
      pa[kc] = pw;
    }
    sum += __shfl_xor(sum, 16, 64);
    sum += __shfl_xor(sum, 32, 64);
    float rs = 1.0f / sum;

    // PV: A-fragment = pa[kc] (own registers, slot perm pi); B = Vt (pi-stored).
    f32x4 o[4];
#pragma unroll
    for (int dt = 0; dt < 4; dt++) o[dt] = (f32x4){0.f, 0.f, 0.f, 0.f};
#pragma unroll
    for (int kc = 0; kc < 8; ++kc) {
      bf16x8 paf = __builtin_bit_cast(bf16x8, pa[kc]);
#pragma unroll
      for (int dt = 0; dt < 4; ++dt) {
        int d = dt * 16 + (l & 15);
        int sl = (kc * 4 + g) ^ (d & 15);
        bf16x8 vb = *(const bf16x8*)&Vt[d * 256 + sl * 8];
        o[dt] = __builtin_amdgcn_mfma_f32_16x16x32_bf16(paf, vb, o[dt], 0, 0, 0);
      }
    }
    // epilogue: O rows q = q0 + g*4 + r, col d = dt*16 + (l&15);
    // rs lives at lanes with (lane&15)==q -> fetch via shfl.
    float rsq[4];
#pragma unroll
    for (int r = 0; r < 4; ++r)
      rsq[r] = __shfl(rs, (l & 48) | (g * 4 + r), 64);
#pragma unroll
    for (int dt = 0; dt < 4; dt++) {
#pragma unroll
      for (int r = 0; r < 4; r++) {
        int qrow = q0 + g * 4 + r;
        int d = dt * 16 + (l & 15);
        O[(size_t)(bp * 256 + qrow) * 512 + h * 64 + d] = f2bf(o[dt][r] * rsq[r]);
      }
    }
  }
}

// ---------------- launch ----------------

extern "C" void kernel_launch(void* const* d_in, const int* in_sizes, int n_in,
                              void* d_out, int out_size, void* d_ws, size_t ws_size,
                              hipStream_t stream) {
  const float* x    = (const float*)d_in[0];
  const float* wqkv = (const float*)d_in[1];
  const float* wout = (const float*)d_in[2];
  const float* bout = (const float*)d_in[3];
  float* out = (float*)d_out;
  char* ws = (char*)d_ws;

  // ws layout (O overlaps Xb/Wqt, which are dead after GEMM1): total ~134.6 MB
  short* Wot = (short*)(ws);                          //   0.39 MB [384][512]
  short* Xb  = (short*)(ws + 393216);                 //  25.17 MB [32768][384]
  short* Wqt = (short*)(ws + 25559040);               //   1.18 MB [1536][384]
  unsigned short* O = (unsigned short*)(ws + 393216); //  33.55 MB [32768][512]
  short* QKV = (short*)(ws + 33947648);               // 100.66 MB [32768][1536]

  k_cast_x<<<6144, 256, 0, stream>>>(x, Xb, 1572864);
  k_transpose_bf<<<2304, 256, 0, stream>>>(wqkv, Wqt, 384, 1536);
  k_transpose_bf<<<768, 256, 0, stream>>>(wout, Wot, 512, 384);
  // GEMM1: 128x256 tiles -> (32768/128)*(1536/256) = 1536 blocks (%8==0)
  k_gemm<1, 8><<<1536, 256, 0, stream>>>(Xb, Wqt, (unsigned short*)QKV, nullptr, nullptr,
                                         32768, 1536, 384);
  k_attn<<<1024, 512, 0, stream>>>(QKV, O);
  // GEMM2: 128x128 tiles -> (32768/128)*(384/128) = 768 blocks (%8==0)
  k_gemm<0, 4><<<768, 256, 0, stream>>>((const short*)O, Wot, nullptr, out, bout,
                                        32768, 384, 512);
  (void)in_sizes; (void)n_in; (void)out_size; (void)ws_size;
}

// Round 13
// 135.139 us; speedup vs baseline: 1.8331x; 1.8270x over previous
//
#include <hip/hip_runtime.h>
#include <stdint.h>

#define DEVFN __device__ __forceinline__

typedef __attribute__((ext_vector_type(8))) __bf16 bf16x8;
typedef __attribute__((ext_vector_type(8))) short short8;
typedef __attribute__((ext_vector_type(4))) float f32x4;
typedef __attribute__((ext_vector_type(4))) unsigned int u32x4;

DEVFN unsigned short f2bf(float f) {
  union { float f; unsigned u; } v; v.f = f;
  return (unsigned short)((v.u + 0x7FFFu + ((v.u >> 16) & 1u)) >> 16);
}

// global -> LDS direct copy, 16B per lane. Dest must be linear in lane order.
DEVFN void gload_lds16(const void* g, void* l) {
  __builtin_amdgcn_global_load_lds(
      (const __attribute__((address_space(1))) void*)(uintptr_t)g,
      (__attribute__((address_space(3))) void*)(uint32_t)(uintptr_t)l,
      16, 0, 0);
}

// ---------------- prep kernels ----------------

__global__ void k_cast_x(const float* __restrict__ x, short* __restrict__ xb, int n8) {
  int i = blockIdx.x * blockDim.x + threadIdx.x;
  if (i >= n8) return;
  const f32x4* xf = (const f32x4*)x;
  f32x4 a = xf[2 * i], b = xf[2 * i + 1];
  short8 s;
  s[0] = (short)f2bf(a[0]); s[1] = (short)f2bf(a[1]);
  s[2] = (short)f2bf(a[2]); s[3] = (short)f2bf(a[3]);
  s[4] = (short)f2bf(b[0]); s[5] = (short)f2bf(b[1]);
  s[6] = (short)f2bf(b[2]); s[7] = (short)f2bf(b[3]);
  ((short8*)xb)[i] = s;
}

// w[R][C] (f32) -> wt[C][R] (bf16)
__global__ void k_transpose_bf(const float* __restrict__ w, short* __restrict__ wt, int R, int C) {
  int i = blockIdx.x * blockDim.x + threadIdx.x;
  if (i >= R * C) return;
  int c = i / R, r = i - c * R;
  wt[i] = (short)f2bf(w[(size_t)r * C + c]);
}

// ---------------- GEMM: C[M][N] = A[M][K] * Bt[N][K]^T ----------------
// Block tile 128 x (NB*32), BK=32, 256 threads (4 waves), per-wave 64 x (NB*16).
// 3-buffer pipeline, counted vmcnt; T1 XCD swizzle; T2 slot-swizzle.

template <int BF16_OUT, int NB>
__global__ __launch_bounds__(256, NB == 8 ? 2 : 3)
void k_gemm(const short* __restrict__ A, const short* __restrict__ Bt,
            unsigned short* __restrict__ Cb, float* __restrict__ Cf,
            const float* __restrict__ bias, int M, int N, int K) {
  constexpr int BN = NB * 32;          // 256 or 128
  constexpr int BCH = NB / 2;          // B staging chunks per thread (4 or 2)
  __shared__ short As[3][128 * 32];
  __shared__ short Bs[3][BN * 32];
  const int tid = threadIdx.x;
  const int l = tid & 63, w = tid >> 6;
  const int ntile = N / BN;
  // XCD-chunked swizzle (T1): grid % 8 == 0 (1536 / 768).
  const int nwg = gridDim.x, cpx = nwg >> 3;
  const int bid = (blockIdx.x & 7) * cpx + (blockIdx.x >> 3);
  const int mt = bid / ntile, nt = bid % ntile;
  const int m0 = mt << 7, n0 = nt * BN;
  const int wm = (w >> 1) << 6, wn = (w & 1) * (NB * 16);

  f32x4 acc[4][NB];
#pragma unroll
  for (int i = 0; i < 4; i++)
#pragma unroll
    for (int j = 0; j < NB; j++) acc[i][j] = (f32x4){0.f, 0.f, 0.f, 0.f};

  const int nsteps = K >> 5;  // 12 (GEMM1) or 16 (GEMM2)

  auto stage = [&](int buf, int t) {
#pragma unroll
    for (int c = 0; c < 2; ++c) {
      int ch = tid + c * 256;
      int row = ch >> 2;
      int sl = (ch & 3) ^ ((row >> 1) & 3);  // inverse-swizzled source slot
      gload_lds16(A + (size_t)(m0 + row) * K + t * 32 + sl * 8, &As[buf][ch * 8]);
    }
#pragma unroll
    for (int c = 0; c < BCH; ++c) {
      int ch = tid + c * 256;
      int row = ch >> 2;
      int sl = (ch & 3) ^ ((row >> 1) & 3);
      gload_lds16(Bt + (size_t)(n0 + row) * K + t * 32 + sl * 8, &Bs[buf][ch * 8]);
    }
  };
  // swizzled read slot: rows base+(l&15), base%16==0 -> (row>>1)&3 == (l>>1)&3
  const int sp8 = (((l >> 4) ^ ((l >> 1) & 3)) << 3);
  auto compute = [&](int buf) {
    bf16x8 af[4], bfr[NB];
#pragma unroll
    for (int i = 0; i < 4; i++)
      af[i] = *(const bf16x8*)&As[buf][(wm + i * 16 + (l & 15)) * 32 + sp8];
#pragma unroll
    for (int j = 0; j < NB; j++)
      bfr[j] = *(const bf16x8*)&Bs[buf][(wn + j * 16 + (l & 15)) * 32 + sp8];
#pragma unroll
    for (int i = 0; i < 4; i++)
#pragma unroll
      for (int j = 0; j < NB; j++)
        acc[i][j] = __builtin_amdgcn_mfma_f32_16x16x32_bf16(af[i], bfr[j], acc[i][j], 0, 0, 0);
  };

  // prologue: 2 tiles in flight ((2+BCH) gload_lds16 each per thread)
  stage(0, 0);
  stage(1, 1);
#pragma unroll 1
  for (int t = 0; t < nsteps; ++t) {
    // wait for tile-t's (2+BCH) loads; keep tile-(t+1)'s in flight
    if (t + 1 < nsteps) {
      if constexpr (NB == 8)
        asm volatile("s_waitcnt vmcnt(6)" ::: "memory");
      else
        asm volatile("s_waitcnt vmcnt(4)" ::: "memory");
    } else {
      asm volatile("s_waitcnt vmcnt(0)" ::: "memory");
    }
    __builtin_amdgcn_sched_barrier(0);
    __builtin_amdgcn_s_barrier();  // all waves' t-loads done; all done reading buf[t-1]
    __builtin_amdgcn_sched_barrier(0);
    if (t + 2 < nsteps) stage((t + 2) % 3, t + 2);  // overwrites buf[(t-1)%3]: safe post-barrier
    compute(t % 3);
  }

#pragma unroll
  for (int i = 0; i < 4; i++) {
    int mrow = m0 + wm + i * 16 + ((l >> 4) << 2);
#pragma unroll
    for (int j = 0; j < NB; j++) {
      int ncol = n0 + wn + j * 16 + (l & 15);
#pragma unroll
      for (int r = 0; r < 4; r++) {
        if (BF16_OUT) {
          Cb[(size_t)(mrow + r) * N + ncol] = f2bf(acc[i][j][r]);
        } else {
          Cf[(size_t)(mrow + r) * N + ncol] = acc[i][j][r] + bias[ncol];
        }
      }
    }
  }
}

// ---------------- fused attention per (bp, head) ----------------
// qkv[token][1536]: Q at h*64, K at 512+h*64, V at 1024+h*64 (bf16).
// 512 threads = 8 waves; wave w handles q rows [w*32, w*32+32) in 2 iters of 16.
//
// SWAPPED QK^T: S^T = mfma(K, Q) puts S[q=l&15][k=kt*16+g*4+r] in lane
// registers; PV's A-fragment comes from the lane's OWN registers under slot
// permutation pi(k)=g*8+(k&16?4:0)+(k&3), with V staged pi-permuted
// (validated: absmax unchanged since round 10).
//
// SPILL ROOT CAUSE (r10-r12, counters invariant): the un-fenced fully
// unrolled PV loop lets the pre-RA scheduler hoist all 32 vb ds_read_b128
// (128 VGPRs in flight) above the MFMAs -> cap 128 forces spilling of
// pa/s (~218 B/thread/iter scratch = the measured 228MB excess). Round 9's
// per-kc "memory" fences had been clamping this. Fix: sched_barrier(0)
// per kc group -> pressure bound pa(32)+o(16)+4vb(16)+addr ~= 75 regs.
// Cross-kc latency hiding is covered by 16 waves/CU TLP (round-9 regime).

__global__ __launch_bounds__(512, 2)
void k_attn(const short* __restrict__ qkv, unsigned short* __restrict__ O) {
  __shared__ short Kl[256 * 64];        // [kcol][64d], XOR-swizzled 16B slots
  __shared__ short Vt[64 * 256];        // [d][pi(k)], XOR-swizzled 16B slots

  const int tid = threadIdx.x, l = tid & 63, w = tid >> 6;
  const int g = (l >> 4) & 3;
  const int bh = blockIdx.x;
  const int bp = bh >> 3, h = bh & 7;
  const size_t tokbase = (size_t)bp * 256 * 1536;
  const int qoff = h * 64, koff = 512 + h * 64, voff = 1024 + h * 64;

  // stage K: linear LDS dest, inverse-swizzled global source (slot ^= row&7)
#pragma unroll
  for (int c = 0; c < 4; ++c) {
    int ch = tid + c * 512;
    int row = ch >> 3, s = ch & 7;
    int sg = s ^ (row & 7);
    gload_lds16(qkv + tokbase + (size_t)row * 1536 + koff + sg * 8, &Kl[ch * 8]);
  }
  // stage V transposed with pi(k): Vt[d][kc*32 + pos], pos = gg*8+(u&16?4:0)+(u&3),
  // 16B slot (kc*4+gg) XOR-swizzled with (d&15).
#pragma unroll
  for (int c = 0; c < 4; ++c) {
    int ch = tid + c * 512;
    int row = ch >> 3, d0 = (ch & 7) * 8;
    short8 v = *(const short8*)(qkv + tokbase + (size_t)row * 1536 + voff + d0);
    int kc = row >> 5, u = row & 31;
    int gg = (u >> 2) & 3;
    int off = ((u & 16) ? 4 : 0) + (u & 3);
#pragma unroll
    for (int j = 0; j < 8; ++j) {
      int d = d0 + j;
      int sl = (kc * 4 + gg) ^ (d & 15);
      Vt[d * 256 + sl * 8 + off] = v[j];
    }
  }
  __syncthreads();

  const float CEXP = 0.125f * 1.44269504f;  // SCALE * log2(e)

#pragma unroll 1
  for (int it = 0; it < 2; ++it) {
    const int q0 = w * 32 + it * 16;
    bf16x8 qa[2];
#pragma unroll
    for (int dc = 0; dc < 2; ++dc)
      qa[dc] = *(const bf16x8*)(qkv + tokbase + (size_t)(q0 + (l & 15)) * 1536 + qoff +
                                dc * 32 + (l >> 4) * 8);
    // S^T = K Q^T: D[kcol][q] -> lane holds S[q=l&15][k=kt*16+g*4+r]
    f32x4 s[16];
#pragma unroll
    for (int kt = 0; kt < 16; kt++) s[kt] = (f32x4){0.f, 0.f, 0.f, 0.f};
#pragma unroll
    for (int dc = 0; dc < 2; ++dc) {
#pragma unroll
      for (int kt = 0; kt < 16; ++kt) {
        int kcol = kt * 16 + (l & 15);
        int sl = (dc * 4 + (l >> 4)) ^ (kcol & 7);
        bf16x8 kb = *(const bf16x8*)&Kl[kcol * 64 + sl * 8];
        s[kt] = __builtin_amdgcn_mfma_f32_16x16x32_bf16(kb, qa[dc], s[kt], 0, 0, 0);
      }
    }
    // softmax max over k for this lane's q=l&15 (local 64 + 2 shfl)
    float mx = s[0][0];
#pragma unroll
    for (int kt = 0; kt < 16; kt++)
#pragma unroll
      for (int r = 0; r < 4; r++) mx = fmaxf(mx, s[kt][r]);
    mx = fmaxf(mx, __shfl_xor(mx, 16, 64));
    mx = fmaxf(mx, __shfl_xor(mx, 32, 64));

    // exp + sum + eager bf16 pack: s[] dies progressively here.
    u32x4 pa[8];
    float sum = 0.f;
#pragma unroll
    for (int kc = 0; kc < 8; ++kc) {
      float p0 = exp2f((s[2 * kc][0] - mx) * CEXP);
      float p1 = exp2f((s[2 * kc][1] - mx) * CEXP);
      float p2 = exp2f((s[2 * kc][2] - mx) * CEXP);
      float p3 = exp2f((s[2 * kc][3] - mx) * CEXP);
      float p4 = exp2f((s[2 * kc + 1][0] - mx) * CEXP);
      float p5 = exp2f((s[2 * kc + 1][1] - mx) * CEXP);
      float p6 = exp2f((s[2 * kc + 1][2] - mx) * CEXP);
      float p7 = exp2f((s[2 * kc + 1][3] - mx) * CEXP);
      sum += ((p0 + p1) + (p2 + p3)) + ((p4 + p5) + (p6 + p7));
      u32x4 pw;
      pw[0] = (unsigned)f2bf(p0) | ((unsigned)f2bf(p1) << 16);
      pw[1] = (unsigned)f2bf(p2) | ((unsigned)f2bf(p3) << 16);
      pw[2] = (unsigned)f2bf(p4) | ((unsigned)f2bf(p5) << 16);
      pw[3] = (unsigned)f2bf(p6) | ((unsigned)f2bf(p7) << 16);
      pa[kc] = pw;
    }
    sum += __shfl_xor(sum, 16, 64);
    sum += __shfl_xor(sum, 32, 64);
    float rs = 1.0f / sum;

    // PV: A-fragment = pa[kc] (own registers, slot perm pi); B = Vt (pi-stored).
    // sched_barrier(0) per kc: forbid the scheduler from hoisting later kc's
    // vb loads above this point (the r10-r12 spill mechanism).
    f32x4 o[4];
#pragma unroll
    for (int dt = 0; dt < 4; dt++) o[dt] = (f32x4){0.f, 0.f, 0.f, 0.f};
#pragma unroll
    for (int kc = 0; kc < 8; ++kc) {
      bf16x8 paf = __builtin_bit_cast(bf16x8, pa[kc]);
#pragma unroll
      for (int dt = 0; dt < 4; ++dt) {
        int d = dt * 16 + (l & 15);
        int sl = (kc * 4 + g) ^ (d & 15);
        bf16x8 vb = *(const bf16x8*)&Vt[d * 256 + sl * 8];
        o[dt] = __builtin_amdgcn_mfma_f32_16x16x32_bf16(paf, vb, o[dt], 0, 0, 0);
      }
      __builtin_amdgcn_sched_barrier(0);
    }
    // epilogue: O rows q = q0 + g*4 + r, col d = dt*16 + (l&15);
    // rs lives at lanes with (lane&15)==q -> fetch via shfl.
    float rsq[4];
#pragma unroll
    for (int r = 0; r < 4; ++r)
      rsq[r] = __shfl(rs, (l & 48) | (g * 4 + r), 64);
#pragma unroll
    for (int dt = 0; dt < 4; dt++) {
#pragma unroll
      for (int r = 0; r < 4; r++) {
        int qrow = q0 + g * 4 + r;
        int d = dt * 16 + (l & 15);
        O[(size_t)(bp * 256 + qrow) * 512 + h * 64 + d] = f2bf(o[dt][r] * rsq[r]);
      }
    }
  }
}

// ---------------- launch ----------------

extern "C" void kernel_launch(void* const* d_in, const int* in_sizes, int n_in,
                              void* d_out, int out_size, void* d_ws, size_t ws_size,
                              hipStream_t stream) {
  const float* x    = (const float*)d_in[0];
  const float* wqkv = (const float*)d_in[1];
  const float* wout = (const float*)d_in[2];
  const float* bout = (const float*)d_in[3];
  float* out = (float*)d_out;
  char* ws = (char*)d_ws;

  // ws layout (O overlaps Xb/Wqt, which are dead after GEMM1): total ~134.6 MB
  short* Wot = (short*)(ws);                          //   0.39 MB [384][512]
  short* Xb  = (short*)(ws + 393216);                 //  25.17 MB [32768][384]
  short* Wqt = (short*)(ws + 25559040);               //   1.18 MB [1536][384]
  unsigned short* O = (unsigned short*)(ws + 393216); //  33.55 MB [32768][512]
  short* QKV = (short*)(ws + 33947648);               // 100.66 MB [32768][1536]

  k_cast_x<<<6144, 256, 0, stream>>>(x, Xb, 1572864);
  k_transpose_bf<<<2304, 256, 0, stream>>>(wqkv, Wqt, 384, 1536);
  k_transpose_bf<<<768, 256, 0, stream>>>(wout, Wot, 512, 384);
  // GEMM1: 128x256 tiles -> (32768/128)*(1536/256) = 1536 blocks (%8==0)
  k_gemm<1, 8><<<1536, 256, 0, stream>>>(Xb, Wqt, (unsigned short*)QKV, nullptr, nullptr,
                                         32768, 1536, 384);
  k_attn<<<1024, 512, 0, stream>>>(QKV, O);
  // GEMM2: 128x128 tiles -> (32768/128)*(384/128) = 768 blocks (%8==0)
  k_gemm<0, 4><<<768, 256, 0, stream>>>((const short*)O, Wot, nullptr, out, bout,
                                        32768, 384, 512);
  (void)in_sizes; (void)n_in; (void)out_size; (void)ws_size;
}

// Round 14
// 130.279 us; speedup vs baseline: 1.9015x; 1.0373x over previous
//
#include <hip/hip_runtime.h>
#include <stdint.h>

#define DEVFN __device__ __forceinline__

typedef __attribute__((ext_vector_type(8))) __bf16 bf16x8;
typedef __attribute__((ext_vector_type(8))) short short8;
typedef __attribute__((ext_vector_type(4))) float f32x4;
typedef __attribute__((ext_vector_type(4))) unsigned int u32x4;

DEVFN unsigned short f2bf(float f) {
  union { float f; unsigned u; } v; v.f = f;
  return (unsigned short)((v.u + 0x7FFFu + ((v.u >> 16) & 1u)) >> 16);
}

// global -> LDS direct copy, 16B per lane. Dest must be linear in lane order.
DEVFN void gload_lds16(const void* g, void* l) {
  __builtin_amdgcn_global_load_lds(
      (const __attribute__((address_space(1))) void*)(uintptr_t)g,
      (__attribute__((address_space(3))) void*)(uint32_t)(uintptr_t)l,
      16, 0, 0);
}

// ---------------- prep ----------------

// w[R][C] (f32) -> wt[C][R] (bf16)
__global__ void k_transpose_bf(const float* __restrict__ w, short* __restrict__ wt, int R, int C) {
  int i = blockIdx.x * blockDim.x + threadIdx.x;
  if (i >= R * C) return;
  int c = i / R, r = i - c * R;
  wt[i] = (short)f2bf(w[(size_t)r * C + c]);
}

// ---------------- GEMM1 (fused f32->bf16 A-cast): QKV = X * Wqt^T ----------
// X[32768][384] f32, Wqt[1536][384] bf16, C bf16 [32768][1536].
// 128x256 tile, BK=32, 256 thr (4 waves, per-wave 64x128), 3-buffer pipeline.
// A is reg-staged (global f32 -> f2bf pack -> ds_write_b128) replacing the
// separate k_cast_x pass (saves 75 MB HBM); B stays gload_lds. Same LDS
// layout + T2 slot swizzle as before (swizzle applied on SOURCE slot).
// vmcnt recount: per iter issue order [A-regs(t+2) x4, B-glds(t+2) x4];
// steady wait vmcnt(4) drains A-regs(t+1) + B(t); lgkmcnt(0) before barrier
// publishes last iter's ds_writes.

#define LOADA(A0, A1, A2, A3, T)                                             \
  do {                                                                       \
    const float* bA = X + (size_t)(m0 + rowA) * 384 + (T) * 32 + slA * 8;    \
    A0 = *(const f32x4*)bA;                                                  \
    A1 = *(const f32x4*)(bA + 4);                                            \
    A2 = *(const f32x4*)(bA + 64 * 384);                                     \
    A3 = *(const f32x4*)(bA + 64 * 384 + 4);                                 \
  } while (0)

#define WRITEA(BUF, A0, A1, A2, A3)                                          \
  do {                                                                       \
    u32x4 w0_;                                                               \
    w0_[0] = (unsigned)f2bf(A0[0]) | ((unsigned)f2bf(A0[1]) << 16);          \
    w0_[1] = (unsigned)f2bf(A0[2]) | ((unsigned)f2bf(A0[3]) << 16);          \
    w0_[2] = (unsigned)f2bf(A1[0]) | ((unsigned)f2bf(A1[1]) << 16);          \
    w0_[3] = (unsigned)f2bf(A1[2]) | ((unsigned)f2bf(A1[3]) << 16);          \
    *(u32x4*)&As[BUF][tid * 8] = w0_;                                        \
    u32x4 w1_;                                                               \
    w1_[0] = (unsigned)f2bf(A2[0]) | ((unsigned)f2bf(A2[1]) << 16);          \
    w1_[1] = (unsigned)f2bf(A2[2]) | ((unsigned)f2bf(A2[3]) << 16);          \
    w1_[2] = (unsigned)f2bf(A3[0]) | ((unsigned)f2bf(A3[1]) << 16);          \
    w1_[3] = (unsigned)f2bf(A3[2]) | ((unsigned)f2bf(A3[3]) << 16);          \
    *(u32x4*)&As[BUF][(tid + 256) * 8] = w1_;                                \
  } while (0)

// Full-pipeline step, valid for T <= 9 (T+2 < 12).
#define STEP_MAIN(T, C0, C1, C2, C3, N0, N1, N2, N3)                         \
  do {                                                                       \
    asm volatile("s_waitcnt vmcnt(4) lgkmcnt(0)" ::: "memory");              \
    __builtin_amdgcn_sched_barrier(0);                                       \
    __builtin_amdgcn_s_barrier();                                            \
    __builtin_amdgcn_sched_barrier(0);                                       \
    LOADA(N0, N1, N2, N3, (T) + 2);                                          \
    stageB(((T) + 2) % 3, (T) + 2);                                          \
    WRITEA(((T) + 1) % 3, C0, C1, C2, C3);                                   \
    compute((T) % 3);                                                        \
  } while (0)

__global__ __launch_bounds__(256, 2)
void k_gemm1(const float* __restrict__ X, const short* __restrict__ Bt,
             unsigned short* __restrict__ Cb) {
  __shared__ short As[3][128 * 32];
  __shared__ short Bs[3][256 * 32];
  const int tid = threadIdx.x, l = tid & 63, w = tid >> 6;
  // T1 XCD-chunked swizzle; grid 1536 % 8 == 0.
  const int nwg = gridDim.x, cpx = nwg >> 3;
  const int bid = (blockIdx.x & 7) * cpx + (blockIdx.x >> 3);
  const int mt = bid / 6, nt = bid % 6;
  const int m0 = mt << 7, n0 = nt * 256;
  const int wm = (w >> 1) << 6, wn = (w & 1) * 128;
  const int rowA = tid >> 2;
  const int slA = (tid & 3) ^ ((rowA >> 1) & 3);  // source-side T2 swizzle

  f32x4 acc[4][8];
#pragma unroll
  for (int i = 0; i < 4; i++)
#pragma unroll
    for (int j = 0; j < 8; j++) acc[i][j] = (f32x4){0.f, 0.f, 0.f, 0.f};

  auto stageB = [&](int buf, int t) {
#pragma unroll
    for (int c = 0; c < 4; ++c) {
      int ch = tid + c * 256;
      int row = ch >> 2;
      int sl = (ch & 3) ^ ((row >> 1) & 3);
      gload_lds16(Bt + (size_t)(n0 + row) * 384 + t * 32 + sl * 8, &Bs[buf][ch * 8]);
    }
  };
  const int sp8 = (((l >> 4) ^ ((l >> 1) & 3)) << 3);
  auto compute = [&](int buf) {
    bf16x8 af[4], bfr[8];
#pragma unroll
    for (int i = 0; i < 4; i++)
      af[i] = *(const bf16x8*)&As[buf][(wm + i * 16 + (l & 15)) * 32 + sp8];
#pragma unroll
    for (int j = 0; j < 8; j++)
      bfr[j] = *(const bf16x8*)&Bs[buf][(wn + j * 16 + (l & 15)) * 32 + sp8];
#pragma unroll
    for (int i = 0; i < 4; i++)
#pragma unroll
      for (int j = 0; j < 8; j++)
        acc[i][j] = __builtin_amdgcn_mfma_f32_16x16x32_bf16(af[i], bfr[j], acc[i][j], 0, 0, 0);
  };

  f32x4 a0_, a1_, a2_, a3_, b0_, b1_, b2_, b3_;
  // prologue: A-regs tiles 0,1; B tiles 0,1. FIFO: A0x4 A1x4 B0x4 B1x4.
  LOADA(a0_, a1_, a2_, a3_, 0);
  LOADA(b0_, b1_, b2_, b3_, 1);
  stageB(0, 0);
  stageB(1, 1);
  asm volatile("s_waitcnt vmcnt(12)" ::: "memory");  // drain A0
  WRITEA(0, a0_, a1_, a2_, a3_);

#pragma unroll 1
  for (int tp = 0; tp < 10; tp += 2) {
    STEP_MAIN(tp,     b0_, b1_, b2_, b3_, a0_, a1_, a2_, a3_);
    STEP_MAIN(tp + 1, a0_, a1_, a2_, a3_, b0_, b1_, b2_, b3_);
  }
  // T=10: write tile 11 (in b set), no new issue.
  asm volatile("s_waitcnt vmcnt(4) lgkmcnt(0)" ::: "memory");
  __builtin_amdgcn_sched_barrier(0);
  __builtin_amdgcn_s_barrier();
  __builtin_amdgcn_sched_barrier(0);
  WRITEA(2, b0_, b1_, b2_, b3_);
  compute(1);
  // T=11
  asm volatile("s_waitcnt vmcnt(0) lgkmcnt(0)" ::: "memory");
  __builtin_amdgcn_sched_barrier(0);
  __builtin_amdgcn_s_barrier();
  __builtin_amdgcn_sched_barrier(0);
  compute(2);

#pragma unroll
  for (int i = 0; i < 4; i++) {
    int mrow = m0 + wm + i * 16 + ((l >> 4) << 2);
#pragma unroll
    for (int j = 0; j < 8; j++) {
      int ncol = n0 + wn + j * 16 + (l & 15);
#pragma unroll
      for (int r = 0; r < 4; r++)
        Cb[(size_t)(mrow + r) * 1536 + ncol] = f2bf(acc[i][j][r]);
    }
  }
}

// ---------------- generic GEMM (used for GEMM2): C = A * Bt^T + bias -------
// 128x128 tile, BK=32, 3-buffer pipeline, counted vmcnt, T1+T2 swizzles.

template <int BF16_OUT, int NB>
__global__ __launch_bounds__(256, NB == 8 ? 2 : 3)
void k_gemm(const short* __restrict__ A, const short* __restrict__ Bt,
            unsigned short* __restrict__ Cb, float* __restrict__ Cf,
            const float* __restrict__ bias, int M, int N, int K) {
  constexpr int BN = NB * 32;
  constexpr int BCH = NB / 2;
  __shared__ short As[3][128 * 32];
  __shared__ short Bs[3][BN * 32];
  const int tid = threadIdx.x;
  const int l = tid & 63, w = tid >> 6;
  const int ntile = N / BN;
  const int nwg = gridDim.x, cpx = nwg >> 3;
  const int bid = (blockIdx.x & 7) * cpx + (blockIdx.x >> 3);
  const int mt = bid / ntile, nt = bid % ntile;
  const int m0 = mt << 7, n0 = nt * BN;
  const int wm = (w >> 1) << 6, wn = (w & 1) * (NB * 16);

  f32x4 acc[4][NB];
#pragma unroll
  for (int i = 0; i < 4; i++)
#pragma unroll
    for (int j = 0; j < NB; j++) acc[i][j] = (f32x4){0.f, 0.f, 0.f, 0.f};

  const int nsteps = K >> 5;

  auto stage = [&](int buf, int t) {
#pragma unroll
    for (int c = 0; c < 2; ++c) {
      int ch = tid + c * 256;
      int row = ch >> 2;
      int sl = (ch & 3) ^ ((row >> 1) & 3);
      gload_lds16(A + (size_t)(m0 + row) * K + t * 32 + sl * 8, &As[buf][ch * 8]);
    }
#pragma unroll
    for (int c = 0; c < BCH; ++c) {
      int ch = tid + c * 256;
      int row = ch >> 2;
      int sl = (ch & 3) ^ ((row >> 1) & 3);
      gload_lds16(Bt + (size_t)(n0 + row) * K + t * 32 + sl * 8, &Bs[buf][ch * 8]);
    }
  };
  const int sp8 = (((l >> 4) ^ ((l >> 1) & 3)) << 3);
  auto compute = [&](int buf) {
    bf16x8 af[4], bfr[NB];
#pragma unroll
    for (int i = 0; i < 4; i++)
      af[i] = *(const bf16x8*)&As[buf][(wm + i * 16 + (l & 15)) * 32 + sp8];
#pragma unroll
    for (int j = 0; j < NB; j++)
      bfr[j] = *(const bf16x8*)&Bs[buf][(wn + j * 16 + (l & 15)) * 32 + sp8];
#pragma unroll
    for (int i = 0; i < 4; i++)
#pragma unroll
      for (int j = 0; j < NB; j++)
        acc[i][j] = __builtin_amdgcn_mfma_f32_16x16x32_bf16(af[i], bfr[j], acc[i][j], 0, 0, 0);
  };

  stage(0, 0);
  stage(1, 1);
#pragma unroll 1
  for (int t = 0; t < nsteps; ++t) {
    if (t + 1 < nsteps) {
      if constexpr (NB == 8)
        asm volatile("s_waitcnt vmcnt(6)" ::: "memory");
      else
        asm volatile("s_waitcnt vmcnt(4)" ::: "memory");
    } else {
      asm volatile("s_waitcnt vmcnt(0)" ::: "memory");
    }
    __builtin_amdgcn_sched_barrier(0);
    __builtin_amdgcn_s_barrier();
    __builtin_amdgcn_sched_barrier(0);
    if (t + 2 < nsteps) stage((t + 2) % 3, t + 2);
    compute(t % 3);
  }

#pragma unroll
  for (int i = 0; i < 4; i++) {
    int mrow = m0 + wm + i * 16 + ((l >> 4) << 2);
#pragma unroll
    for (int j = 0; j < NB; j++) {
      int ncol = n0 + wn + j * 16 + (l & 15);
#pragma unroll
      for (int r = 0; r < 4; r++) {
        if (BF16_OUT) {
          Cb[(size_t)(mrow + r) * N + ncol] = f2bf(acc[i][j][r]);
        } else {
          Cf[(size_t)(mrow + r) * N + ncol] = acc[i][j][r] + bias[ncol];
        }
      }
    }
  }
}

// ---------------- fused attention per (bp, head) ----------------
// Round-13 verified version (swapped QK^T + pi-permuted V, eager pack,
// per-kc sched_barrier pressure clamp).

__global__ __launch_bounds__(512, 2)
void k_attn(const short* __restrict__ qkv, unsigned short* __restrict__ O) {
  __shared__ short Kl[256 * 64];
  __shared__ short Vt[64 * 256];

  const int tid = threadIdx.x, l = tid & 63, w = tid >> 6;
  const int g = (l >> 4) & 3;
  const int bh = blockIdx.x;
  const int bp = bh >> 3, h = bh & 7;
  const size_t tokbase = (size_t)bp * 256 * 1536;
  const int qoff = h * 64, koff = 512 + h * 64, voff = 1024 + h * 64;

#pragma unroll
  for (int c = 0; c < 4; ++c) {
    int ch = tid + c * 512;
    int row = ch >> 3, s = ch & 7;
    int sg = s ^ (row & 7);
    gload_lds16(qkv + tokbase + (size_t)row * 1536 + koff + sg * 8, &Kl[ch * 8]);
  }
#pragma unroll
  for (int c = 0; c < 4; ++c) {
    int ch = tid + c * 512;
    int row = ch >> 3, d0 = (ch & 7) * 8;
    short8 v = *(const short8*)(qkv + tokbase + (size_t)row * 1536 + voff + d0);
    int kc = row >> 5, u = row & 31;
    int gg = (u >> 2) & 3;
    int off = ((u & 16) ? 4 : 0) + (u & 3);
#pragma unroll
    for (int j = 0; j < 8; ++j) {
      int d = d0 + j;
      int sl = (kc * 4 + gg) ^ (d & 15);
      Vt[d * 256 + sl * 8 + off] = v[j];
    }
  }
  __syncthreads();

  const float CEXP = 0.125f * 1.44269504f;

#pragma unroll 1
  for (int it = 0; it < 2; ++it) {
    const int q0 = w * 32 + it * 16;
    bf16x8 qa[2];
#pragma unroll
    for (int dc = 0; dc < 2; ++dc)
      qa[dc] = *(const bf16x8*)(qkv + tokbase + (size_t)(q0 + (l & 15)) * 1536 + qoff +
                                dc * 32 + (l >> 4) * 8);
    f32x4 s[16];
#pragma unroll
    for (int kt = 0; kt < 16; kt++) s[kt] = (f32x4){0.f, 0.f, 0.f, 0.f};
#pragma unroll
    for (int dc = 0; dc < 2; ++dc) {
#pragma unroll
      for (int kt = 0; kt < 16; ++kt) {
        int kcol = kt * 16 + (l & 15);
        int sl = (dc * 4 + (l >> 4)) ^ (kcol & 7);
        bf16x8 kb = *(const bf16x8*)&Kl[kcol * 64 + sl * 8];
        s[kt] = __builtin_amdgcn_mfma_f32_16x16x32_bf16(kb, qa[dc], s[kt], 0, 0, 0);
      }
    }
    float mx = s[0][0];
#pragma unroll
    for (int kt = 0; kt < 16; kt++)
#pragma unroll
      for (int r = 0; r < 4; r++) mx = fmaxf(mx, s[kt][r]);
    mx = fmaxf(mx, __shfl_xor(mx, 16, 64));
    mx = fmaxf(mx, __shfl_xor(mx, 32, 64));

    u32x4 pa[8];
    float sum = 0.f;
#pragma unroll
    for (int kc = 0; kc < 8; ++kc) {
      float p0 = exp2f((s[2 * kc][0] - mx) * CEXP);
      float p1 = exp2f((s[2 * kc][1] - mx) * CEXP);
      float p2 = exp2f((s[2 * kc][2] - mx) * CEXP);
      float p3 = exp2f((s[2 * kc][3] - mx) * CEXP);
      float p4 = exp2f((s[2 * kc + 1][0] - mx) * CEXP);
      float p5 = exp2f((s[2 * kc + 1][1] - mx) * CEXP);
      float p6 = exp2f((s[2 * kc + 1][2] - mx) * CEXP);
      float p7 = exp2f((s[2 * kc + 1][3] - mx) * CEXP);
      sum += ((p0 + p1) + (p2 + p3)) + ((p4 + p5) + (p6 + p7));
      u32x4 pw;
      pw[0] = (unsigned)f2bf(p0) | ((unsigned)f2bf(p1) << 16);
      pw[1] = (unsigned)f2bf(p2) | ((unsigned)f2bf(p3) << 16);
      pw[2] = (unsigned)f2bf(p4) | ((unsigned)f2bf(p5) << 16);
      pw[3] = (unsigned)f2bf(p6) | ((unsigned)f2bf(p7) << 16);
      pa[kc] = pw;
    }
    sum += __shfl_xor(sum, 16, 64);
    sum += __shfl_xor(sum, 32, 64);
    float rs = 1.0f / sum;

    f32x4 o[4];
#pragma unroll
    for (int dt = 0; dt < 4; dt++) o[dt] = (f32x4){0.f, 0.f, 0.f, 0.f};
#pragma unroll
    for (int kc = 0; kc < 8; ++kc) {
      bf16x8 paf = __builtin_bit_cast(bf16x8, pa[kc]);
#pragma unroll
      for (int dt = 0; dt < 4; ++dt) {
        int d = dt * 16 + (l & 15);
        int sl = (kc * 4 + g) ^ (d & 15);
        bf16x8 vb = *(const bf16x8*)&Vt[d * 256 + sl * 8];
        o[dt] = __builtin_amdgcn_mfma_f32_16x16x32_bf16(paf, vb, o[dt], 0, 0, 0);
      }
      __builtin_amdgcn_sched_barrier(0);
    }
    float rsq[4];
#pragma unroll
    for (int r = 0; r < 4; ++r)
      rsq[r] = __shfl(rs, (l & 48) | (g * 4 + r), 64);
#pragma unroll
    for (int dt = 0; dt < 4; dt++) {
#pragma unroll
      for (int r = 0; r < 4; r++) {
        int qrow = q0 + g * 4 + r;
        int d = dt * 16 + (l & 15);
        O[(size_t)(bp * 256 + qrow) * 512 + h * 64 + d] = f2bf(o[dt][r] * rsq[r]);
      }
    }
  }
}

// ---------------- launch ----------------

extern "C" void kernel_launch(void* const* d_in, const int* in_sizes, int n_in,
                              void* d_out, int out_size, void* d_ws, size_t ws_size,
                              hipStream_t stream) {
  const float* x    = (const float*)d_in[0];
  const float* wqkv = (const float*)d_in[1];
  const float* wout = (const float*)d_in[2];
  const float* bout = (const float*)d_in[3];
  float* out = (float*)d_out;
  char* ws = (char*)d_ws;

  // ws layout: Xb slot retired (cast fused into k_gemm1).
  short* Wot = (short*)(ws);                          //   0.39 MB [384][512]
  short* Wqt = (short*)(ws + 25559040);               //   1.18 MB [1536][384]
  unsigned short* O = (unsigned short*)(ws + 393216); //  33.55 MB [32768][512]
  short* QKV = (short*)(ws + 33947648);               // 100.66 MB [32768][1536]

  k_transpose_bf<<<2304, 256, 0, stream>>>(wqkv, Wqt, 384, 1536);
  k_transpose_bf<<<768, 256, 0, stream>>>(wout, Wot, 512, 384);
  // GEMM1 (fused cast): 128x256 tiles -> 256*6 = 1536 blocks (%8==0)
  k_gemm1<<<1536, 256, 0, stream>>>(x, Wqt, (unsigned short*)QKV);
  k_attn<<<1024, 512, 0, stream>>>(QKV, O);
  // GEMM2: 128x128 tiles -> 768 blocks (%8==0)
  k_gemm<0, 4><<<768, 256, 0, stream>>>((const short*)O, Wot, nullptr, out, bout,
                                        32768, 384, 512);
  (void)in_sizes; (void)n_in; (void)out_size; (void)ws_size;
}

// Round 15
// 128.290 us; speedup vs baseline: 1.9310x; 1.0155x over previous
//
#include <hip/hip_runtime.h>
#include <stdint.h>

#define DEVFN __device__ __forceinline__

typedef __attribute__((ext_vector_type(8))) __bf16 bf16x8;
typedef __attribute__((ext_vector_type(8))) short short8;
typedef __attribute__((ext_vector_type(4))) float f32x4;
typedef __attribute__((ext_vector_type(4))) unsigned int u32x4;

// Native scalar cast -> hardware v_cvt_pk_bf16_f32 (RNE). The previous
// bit-twiddled RNE (~4 int ops/elem) blocked the pattern match and put
// ~128 serial VALU ops per K-step on k_gemm1's issue path (m240 lesson:
// don't hand-write bf16 conversion).
DEVFN unsigned short f2bf(float f) {
  return __builtin_bit_cast(unsigned short, (__bf16)f);
}

// global -> LDS direct copy, 16B per lane. Dest must be linear in lane order.
DEVFN void gload_lds16(const void* g, void* l) {
  __builtin_amdgcn_global_load_lds(
      (const __attribute__((address_space(1))) void*)(uintptr_t)g,
      (__attribute__((address_space(3))) void*)(uint32_t)(uintptr_t)l,
      16, 0, 0);
}

// ---------------- prep ----------------

// w[R][C] (f32) -> wt[C][R] (bf16)
__global__ void k_transpose_bf(const float* __restrict__ w, short* __restrict__ wt, int R, int C) {
  int i = blockIdx.x * blockDim.x + threadIdx.x;
  if (i >= R * C) return;
  int c = i / R, r = i - c * R;
  wt[i] = (short)f2bf(w[(size_t)r * C + c]);
}

// ---------------- GEMM1 (fused f32->bf16 A-cast): QKV = X * Wqt^T ----------
// X[32768][384] f32, Wqt[1536][384] bf16, C bf16 [32768][1536].
// 128x256 tile, BK=32, 256 thr (4 waves, per-wave 64x128), 3-buffer pipeline.
// A reg-staged (global f32 -> cvt_pk pack -> ds_write_b128); B gload_lds.
// T1 XCD swizzle + T2 source-slot swizzle. vmcnt: steady wait vmcnt(4)
// drains A-regs(t+1)+B(t); lgkmcnt(0) publishes last iter's ds_writes.

#define LOADA(A0, A1, A2, A3, T)                                             \
  do {                                                                       \
    const float* bA = X + (size_t)(m0 + rowA) * 384 + (T) * 32 + slA * 8;    \
    A0 = *(const f32x4*)bA;                                                  \
    A1 = *(const f32x4*)(bA + 4);                                            \
    A2 = *(const f32x4*)(bA + 64 * 384);                                     \
    A3 = *(const f32x4*)(bA + 64 * 384 + 4);                                 \
  } while (0)

#define WRITEA(BUF, A0, A1, A2, A3)                                          \
  do {                                                                       \
    u32x4 w0_;                                                               \
    w0_[0] = (unsigned)f2bf(A0[0]) | ((unsigned)f2bf(A0[1]) << 16);          \
    w0_[1] = (unsigned)f2bf(A0[2]) | ((unsigned)f2bf(A0[3]) << 16);          \
    w0_[2] = (unsigned)f2bf(A1[0]) | ((unsigned)f2bf(A1[1]) << 16);          \
    w0_[3] = (unsigned)f2bf(A1[2]) | ((unsigned)f2bf(A1[3]) << 16);          \
    *(u32x4*)&As[BUF][tid * 8] = w0_;                                        \
    u32x4 w1_;                                                               \
    w1_[0] = (unsigned)f2bf(A2[0]) | ((unsigned)f2bf(A2[1]) << 16);          \
    w1_[1] = (unsigned)f2bf(A2[2]) | ((unsigned)f2bf(A2[3]) << 16);          \
    w1_[2] = (unsigned)f2bf(A3[0]) | ((unsigned)f2bf(A3[1]) << 16);          \
    w1_[3] = (unsigned)f2bf(A3[2]) | ((unsigned)f2bf(A3[3]) << 16);          \
    *(u32x4*)&As[BUF][(tid + 256) * 8] = w1_;                                \
  } while (0)

// Full-pipeline step, valid for T <= 9 (T+2 < 12).
#define STEP_MAIN(T, C0, C1, C2, C3, N0, N1, N2, N3)                         \
  do {                                                                       \
    asm volatile("s_waitcnt vmcnt(4) lgkmcnt(0)" ::: "memory");              \
    __builtin_amdgcn_sched_barrier(0);                                       \
    __builtin_amdgcn_s_barrier();                                            \
    __builtin_amdgcn_sched_barrier(0);                                       \
    LOADA(N0, N1, N2, N3, (T) + 2);                                          \
    stageB(((T) + 2) % 3, (T) + 2);                                          \
    WRITEA(((T) + 1) % 3, C0, C1, C2, C3);                                   \
    compute((T) % 3);                                                        \
  } while (0)

__global__ __launch_bounds__(256, 2)
void k_gemm1(const float* __restrict__ X, const short* __restrict__ Bt,
             unsigned short* __restrict__ Cb) {
  __shared__ short As[3][128 * 32];
  __shared__ short Bs[3][256 * 32];
  const int tid = threadIdx.x, l = tid & 63, w = tid >> 6;
  // T1 XCD-chunked swizzle; grid 1536 % 8 == 0.
  const int nwg = gridDim.x, cpx = nwg >> 3;
  const int bid = (blockIdx.x & 7) * cpx + (blockIdx.x >> 3);
  const int mt = bid / 6, nt = bid % 6;
  const int m0 = mt << 7, n0 = nt * 256;
  const int wm = (w >> 1) << 6, wn = (w & 1) * 128;
  const int rowA = tid >> 2;
  const int slA = (tid & 3) ^ ((rowA >> 1) & 3);  // source-side T2 swizzle

  f32x4 acc[4][8];
#pragma unroll
  for (int i = 0; i < 4; i++)
#pragma unroll
    for (int j = 0; j < 8; j++) acc[i][j] = (f32x4){0.f, 0.f, 0.f, 0.f};

  auto stageB = [&](int buf, int t) {
#pragma unroll
    for (int c = 0; c < 4; ++c) {
      int ch = tid + c * 256;
      int row = ch >> 2;
      int sl = (ch & 3) ^ ((row >> 1) & 3);
      gload_lds16(Bt + (size_t)(n0 + row) * 384 + t * 32 + sl * 8, &Bs[buf][ch * 8]);
    }
  };
  const int sp8 = (((l >> 4) ^ ((l >> 1) & 3)) << 3);
  auto compute = [&](int buf) {
    bf16x8 af[4], bfr[8];
#pragma unroll
    for (int i = 0; i < 4; i++)
      af[i] = *(const bf16x8*)&As[buf][(wm + i * 16 + (l & 15)) * 32 + sp8];
#pragma unroll
    for (int j = 0; j < 8; j++)
      bfr[j] = *(const bf16x8*)&Bs[buf][(wn + j * 16 + (l & 15)) * 32 + sp8];
#pragma unroll
    for (int i = 0; i < 4; i++)
#pragma unroll
      for (int j = 0; j < 8; j++)
        acc[i][j] = __builtin_amdgcn_mfma_f32_16x16x32_bf16(af[i], bfr[j], acc[i][j], 0, 0, 0);
  };

  f32x4 a0_, a1_, a2_, a3_, b0_, b1_, b2_, b3_;
  // prologue: A-regs tiles 0,1; B tiles 0,1. FIFO: A0x4 A1x4 B0x4 B1x4.
  LOADA(a0_, a1_, a2_, a3_, 0);
  LOADA(b0_, b1_, b2_, b3_, 1);
  stageB(0, 0);
  stageB(1, 1);
  asm volatile("s_waitcnt vmcnt(12)" ::: "memory");  // drain A0
  WRITEA(0, a0_, a1_, a2_, a3_);

#pragma unroll 1
  for (int tp = 0; tp < 10; tp += 2) {
    STEP_MAIN(tp,     b0_, b1_, b2_, b3_, a0_, a1_, a2_, a3_);
    STEP_MAIN(tp + 1, a0_, a1_, a2_, a3_, b0_, b1_, b2_, b3_);
  }
  // T=10: write tile 11 (in b set), no new issue.
  asm volatile("s_waitcnt vmcnt(4) lgkmcnt(0)" ::: "memory");
  __builtin_amdgcn_sched_barrier(0);
  __builtin_amdgcn_s_barrier();
  __builtin_amdgcn_sched_barrier(0);
  WRITEA(2, b0_, b1_, b2_, b3_);
  compute(1);
  // T=11
  asm volatile("s_waitcnt vmcnt(0) lgkmcnt(0)" ::: "memory");
  __builtin_amdgcn_sched_barrier(0);
  __builtin_amdgcn_s_barrier();
  __builtin_amdgcn_sched_barrier(0);
  compute(2);

#pragma unroll
  for (int i = 0; i < 4; i++) {
    int mrow = m0 + wm + i * 16 + ((l >> 4) << 2);
#pragma unroll
    for (int j = 0; j < 8; j++) {
      int ncol = n0 + wn + j * 16 + (l & 15);
#pragma unroll
      for (int r = 0; r < 4; r++)
        Cb[(size_t)(mrow + r) * 1536 + ncol] = f2bf(acc[i][j][r]);
    }
  }
}

// ---------------- generic GEMM (used for GEMM2): C = A * Bt^T + bias -------
// 128x128 tile, BK=32, 3-buffer pipeline, counted vmcnt, T1+T2 swizzles.

template <int BF16_OUT, int NB>
__global__ __launch_bounds__(256, NB == 8 ? 2 : 3)
void k_gemm(const short* __restrict__ A, const short* __restrict__ Bt,
            unsigned short* __restrict__ Cb, float* __restrict__ Cf,
            const float* __restrict__ bias, int M, int N, int K) {
  constexpr int BN = NB * 32;
  constexpr int BCH = NB / 2;
  __shared__ short As[3][128 * 32];
  __shared__ short Bs[3][BN * 32];
  const int tid = threadIdx.x;
  const int l = tid & 63, w = tid >> 6;
  const int ntile = N / BN;
  const int nwg = gridDim.x, cpx = nwg >> 3;
  const int bid = (blockIdx.x & 7) * cpx + (blockIdx.x >> 3);
  const int mt = bid / ntile, nt = bid % ntile;
  const int m0 = mt << 7, n0 = nt * BN;
  const int wm = (w >> 1) << 6, wn = (w & 1) * (NB * 16);

  f32x4 acc[4][NB];
#pragma unroll
  for (int i = 0; i < 4; i++)
#pragma unroll
    for (int j = 0; j < NB; j++) acc[i][j] = (f32x4){0.f, 0.f, 0.f, 0.f};

  const int nsteps = K >> 5;

  auto stage = [&](int buf, int t) {
#pragma unroll
    for (int c = 0; c < 2; ++c) {
      int ch = tid + c * 256;
      int row = ch >> 2;
      int sl = (ch & 3) ^ ((row >> 1) & 3);
      gload_lds16(A + (size_t)(m0 + row) * K + t * 32 + sl * 8, &As[buf][ch * 8]);
    }
#pragma unroll
    for (int c = 0; c < BCH; ++c) {
      int ch = tid + c * 256;
      int row = ch >> 2;
      int sl = (ch & 3) ^ ((row >> 1) & 3);
      gload_lds16(Bt + (size_t)(n0 + row) * K + t * 32 + sl * 8, &Bs[buf][ch * 8]);
    }
  };
  const int sp8 = (((l >> 4) ^ ((l >> 1) & 3)) << 3);
  auto compute = [&](int buf) {
    bf16x8 af[4], bfr[NB];
#pragma unroll
    for (int i = 0; i < 4; i++)
      af[i] = *(const bf16x8*)&As[buf][(wm + i * 16 + (l & 15)) * 32 + sp8];
#pragma unroll
    for (int j = 0; j < NB; j++)
      bfr[j] = *(const bf16x8*)&Bs[buf][(wn + j * 16 + (l & 15)) * 32 + sp8];
#pragma unroll
    for (int i = 0; i < 4; i++)
#pragma unroll
      for (int j = 0; j < NB; j++)
        acc[i][j] = __builtin_amdgcn_mfma_f32_16x16x32_bf16(af[i], bfr[j], acc[i][j], 0, 0, 0);
  };

  stage(0, 0);
  stage(1, 1);
#pragma unroll 1
  for (int t = 0; t < nsteps; ++t) {
    if (t + 1 < nsteps) {
      if constexpr (NB == 8)
        asm volatile("s_waitcnt vmcnt(6)" ::: "memory");
      else
        asm volatile("s_waitcnt vmcnt(4)" ::: "memory");
    } else {
      asm volatile("s_waitcnt vmcnt(0)" ::: "memory");
    }
    __builtin_amdgcn_sched_barrier(0);
    __builtin_amdgcn_s_barrier();
    __builtin_amdgcn_sched_barrier(0);
    if (t + 2 < nsteps) stage((t + 2) % 3, t + 2);
    compute(t % 3);
  }

#pragma unroll
  for (int i = 0; i < 4; i++) {
    int mrow = m0 + wm + i * 16 + ((l >> 4) << 2);
#pragma unroll
    for (int j = 0; j < NB; j++) {
      int ncol = n0 + wn + j * 16 + (l & 15);
#pragma unroll
      for (int r = 0; r < 4; r++) {
        if (BF16_OUT) {
          Cb[(size_t)(mrow + r) * N + ncol] = f2bf(acc[i][j][r]);
        } else {
          Cf[(size_t)(mrow + r) * N + ncol] = acc[i][j][r] + bias[ncol];
        }
      }
    }
  }
}

// ---------------- fused attention per (bp, head) ----------------
// Round-13 verified version (swapped QK^T + pi-permuted V, eager pack,
// per-kc sched_barrier pressure clamp).

__global__ __launch_bounds__(512, 2)
void k_attn(const short* __restrict__ qkv, unsigned short* __restrict__ O) {
  __shared__ short Kl[256 * 64];
  __shared__ short Vt[64 * 256];

  const int tid = threadIdx.x, l = tid & 63, w = tid >> 6;
  const int g = (l >> 4) & 3;
  const int bh = blockIdx.x;
  const int bp = bh >> 3, h = bh & 7;
  const size_t tokbase = (size_t)bp * 256 * 1536;
  const int qoff = h * 64, koff = 512 + h * 64, voff = 1024 + h * 64;

#pragma unroll
  for (int c = 0; c < 4; ++c) {
    int ch = tid + c * 512;
    int row = ch >> 3, s = ch & 7;
    int sg = s ^ (row & 7);
    gload_lds16(qkv + tokbase + (size_t)row * 1536 + koff + sg * 8, &Kl[ch * 8]);
  }
#pragma unroll
  for (int c = 0; c < 4; ++c) {
    int ch = tid + c * 512;
    int row = ch >> 3, d0 = (ch & 7) * 8;
    short8 v = *(const short8*)(qkv + tokbase + (size_t)row * 1536 + voff + d0);
    int kc = row >> 5, u = row & 31;
    int gg = (u >> 2) & 3;
    int off = ((u & 16) ? 4 : 0) + (u & 3);
#pragma unroll
    for (int j = 0; j < 8; ++j) {
      int d = d0 + j;
      int sl = (kc * 4 + gg) ^ (d & 15);
      Vt[d * 256 + sl * 8 + off] = v[j];
    }
  }
  __syncthreads();

  const float CEXP = 0.125f * 1.44269504f;

#pragma unroll 1
  for (int it = 0; it < 2; ++it) {
    const int q0 = w * 32 + it * 16;
    bf16x8 qa[2];
#pragma unroll
    for (int dc = 0; dc < 2; ++dc)
      qa[dc] = *(const bf16x8*)(qkv + tokbase + (size_t)(q0 + (l & 15)) * 1536 + qoff +
                                dc * 32 + (l >> 4) * 8);
    f32x4 s[16];
#pragma unroll
    for (int kt = 0; kt < 16; kt++) s[kt] = (f32x4){0.f, 0.f, 0.f, 0.f};
#pragma unroll
    for (int dc = 0; dc < 2; ++dc) {
#pragma unroll
      for (int kt = 0; kt < 16; ++kt) {
        int kcol = kt * 16 + (l & 15);
        int sl = (dc * 4 + (l >> 4)) ^ (kcol & 7);
        bf16x8 kb = *(const bf16x8*)&Kl[kcol * 64 + sl * 8];
        s[kt] = __builtin_amdgcn_mfma_f32_16x16x32_bf16(kb, qa[dc], s[kt], 0, 0, 0);
      }
    }
    float mx = s[0][0];
#pragma unroll
    for (int kt = 0; kt < 16; kt++)
#pragma unroll
      for (int r = 0; r < 4; r++) mx = fmaxf(mx, s[kt][r]);
    mx = fmaxf(mx, __shfl_xor(mx, 16, 64));
    mx = fmaxf(mx, __shfl_xor(mx, 32, 64));

    u32x4 pa[8];
    float sum = 0.f;
#pragma unroll
    for (int kc = 0; kc < 8; ++kc) {
      float p0 = exp2f((s[2 * kc][0] - mx) * CEXP);
      float p1 = exp2f((s[2 * kc][1] - mx) * CEXP);
      float p2 = exp2f((s[2 * kc][2] - mx) * CEXP);
      float p3 = exp2f((s[2 * kc][3] - mx) * CEXP);
      float p4 = exp2f((s[2 * kc + 1][0] - mx) * CEXP);
      float p5 = exp2f((s[2 * kc + 1][1] - mx) * CEXP);
      float p6 = exp2f((s[2 * kc + 1][2] - mx) * CEXP);
      float p7 = exp2f((s[2 * kc + 1][3] - mx) * CEXP);
      sum += ((p0 + p1) + (p2 + p3)) + ((p4 + p5) + (p6 + p7));
      u32x4 pw;
      pw[0] = (unsigned)f2bf(p0) | ((unsigned)f2bf(p1) << 16);
      pw[1] = (unsigned)f2bf(p2) | ((unsigned)f2bf(p3) << 16);
      pw[2] = (unsigned)f2bf(p4) | ((unsigned)f2bf(p5) << 16);
      pw[3] = (unsigned)f2bf(p6) | ((unsigned)f2bf(p7) << 16);
      pa[kc] = pw;
    }
    sum += __shfl_xor(sum, 16, 64);
    sum += __shfl_xor(sum, 32, 64);
    float rs = 1.0f / sum;

    f32x4 o[4];
#pragma unroll
    for (int dt = 0; dt < 4; dt++) o[dt] = (f32x4){0.f, 0.f, 0.f, 0.f};
#pragma unroll
    for (int kc = 0; kc < 8; ++kc) {
      bf16x8 paf = __builtin_bit_cast(bf16x8, pa[kc]);
#pragma unroll
      for (int dt = 0; dt < 4; ++dt) {
        int d = dt * 16 + (l & 15);
        int sl = (kc * 4 + g) ^ (d & 15);
        bf16x8 vb = *(const bf16x8*)&Vt[d * 256 + sl * 8];
        o[dt] = __builtin_amdgcn_mfma_f32_16x16x32_bf16(paf, vb, o[dt], 0, 0, 0);
      }
      __builtin_amdgcn_sched_barrier(0);
    }
    float rsq[4];
#pragma unroll
    for (int r = 0; r < 4; ++r)
      rsq[r] = __shfl(rs, (l & 48) | (g * 4 + r), 64);
#pragma unroll
    for (int dt = 0; dt < 4; dt++) {
#pragma unroll
      for (int r = 0; r < 4; r++) {
        int qrow = q0 + g * 4 + r;
        int d = dt * 16 + (l & 15);
        O[(size_t)(bp * 256 + qrow) * 512 + h * 64 + d] = f2bf(o[dt][r] * rsq[r]);
      }
    }
  }
}

// ---------------- launch ----------------

extern "C" void kernel_launch(void* const* d_in, const int* in_sizes, int n_in,
                              void* d_out, int out_size, void* d_ws, size_t ws_size,
                              hipStream_t stream) {
  const float* x    = (const float*)d_in[0];
  const float* wqkv = (const float*)d_in[1];
  const float* wout = (const float*)d_in[2];
  const float* bout = (const float*)d_in[3];
  float* out = (float*)d_out;
  char* ws = (char*)d_ws;

  // ws layout: Xb slot retired (cast fused into k_gemm1).
  short* Wot = (short*)(ws);                          //   0.39 MB [384][512]
  short* Wqt = (short*)(ws + 25559040);               //   1.18 MB [1536][384]
  unsigned short* O = (unsigned short*)(ws + 393216); //  33.55 MB [32768][512]
  short* QKV = (short*)(ws + 33947648);               // 100.66 MB [32768][1536]

  k_transpose_bf<<<2304, 256, 0, stream>>>(wqkv, Wqt, 384, 1536);
  k_transpose_bf<<<768, 256, 0, stream>>>(wout, Wot, 512, 384);
  // GEMM1 (fused cast): 128x256 tiles -> 256*6 = 1536 blocks (%8==0)
  k_gemm1<<<1536, 256, 0, stream>>>(x, Wqt, (unsigned short*)QKV);
  k_attn<<<1024, 512, 0, stream>>>(QKV, O);
  // GEMM2: 128x128 tiles -> 768 blocks (%8==0)
  k_gemm<0, 4><<<768, 256, 0, stream>>>((const short*)O, Wot, nullptr, out, bout,
                                        32768, 384, 512);
  (void)in_sizes; (void)n_in; (void)out_size; (void)ws_size;
}